// Round 2
// baseline (1263.281 us; speedup 1.0000x reference)
//
#include <hip/hip_runtime.h>
#include <math.h>

#define TL 131072

// Output layout (flat f32 element offsets into d_out):
//   recon   [TL,16]      @ 0
//   pred    [TL,16]      @ TL*16
//   lm_pred [2,TL,8]     @ TL*32
//   lv_pred [2,TL,8]     @ TL*48
//   Ct      [TL,16,8]    @ TL*64   (binarized)
//   Ct_1    [TL,16,8]    @ TL*192  (continuous)
static constexpr size_t OFF_RECON = 0;
static constexpr size_t OFF_PRED  = (size_t)TL * 16;
static constexpr size_t OFF_LMP   = (size_t)TL * 32;
static constexpr size_t OFF_LVP   = (size_t)TL * 48;
static constexpr size_t OFF_CT    = (size_t)TL * 64;
static constexpr size_t OFF_CT1   = (size_t)TL * 192;

struct Params {
  const float* lm;  const float* lv;  const float* Tin;
  const float* cw0; const float* cb0; const float* cw1; const float* cb1; const float* cw2; const float* cb2;
  const float* pw0; const float* pb0; const float* pw1; const float* pb1; const float* pw2; const float* pb2;
  const float* fmw1; const float* fmb1; const float* fmw2; const float* fmb2;
  const float* fvw1; const float* fvb1; const float* fvw2; const float* fvb2;
  const float* lw0; const float* lb0; const float* lw1; const float* lb1; const float* lw2; const float* lb2;
  float* out;
};

__device__ __forceinline__ void load8(const float* __restrict__ src, float* dst) {
  float4 a = reinterpret_cast<const float4*>(src)[0];
  float4 b = reinterpret_cast<const float4*>(src)[1];
  dst[0]=a.x; dst[1]=a.y; dst[2]=a.z; dst[3]=a.w;
  dst[4]=b.x; dst[5]=b.y; dst[6]=b.z; dst[7]=b.w;
}

__device__ __forceinline__ void store8(float* __restrict__ dst, const float* v) {
  float4 a = {v[0],v[1],v[2],v[3]};
  float4 b = {v[4],v[5],v[6],v[7]};
  reinterpret_cast<float4*>(dst)[0] = a;
  reinterpret_cast<float4*>(dst)[1] = b;
}

__global__ __launch_bounds__(256, 4) void tld_fused(Params p) {
  __shared__ float s_w12[16 * 64];
  __shared__ float s_b12[16];

  // ---- collapse decoder layers 1+2 (no relu between them in the reference):
  // w12[n][h] = sum_o lw1[n][h][o]*lw2[n][o]; b12[n] = lb2[n] + sum_o lb1[n][o]*lw2[n][o]
  for (int i = threadIdx.x; i < 16 * 64; i += 256) {
    int n = i >> 6, h = i & 63;
    float s = 0.f;
    #pragma unroll 8
    for (int o = 0; o < 64; ++o)
      s = fmaf(p.lw1[n * 4096 + h * 64 + o], p.lw2[n * 64 + o], s);
    s_w12[i] = s;
  }
  if (threadIdx.x < 16) {
    int n = threadIdx.x;
    float b = p.lb2[n];
    #pragma unroll 8
    for (int o = 0; o < 64; ++o)
      b = fmaf(p.lb1[n * 64 + o], p.lw2[n * 64 + o], b);
    s_b12[n] = b;
  }
  __syncthreads();

  const int t    = blockIdx.x * 128 + (threadIdx.x & 127);
  // role is uniform per wave (threads 0-127 role0, 128-255 role1);
  // readfirstlane makes it an SGPR so weight selects/branches go scalar.
  const int role = __builtin_amdgcn_readfirstlane((int)(threadIdx.x >> 7));

  const float* ew0 = role ? p.pw0 : p.cw0;
  const float* eb0 = role ? p.pb0 : p.cb0;
  const float* ew1 = role ? p.pw1 : p.cw1;
  const float* eb1 = role ? p.pb1 : p.cb1;
  const float* ew2 = role ? p.pw2 : p.cw2;
  const float* eb2 = role ? p.pb2 : p.cb2;
  const float* hw1 = role ? p.fvw1 : p.fmw1;
  const float* hb1 = role ? p.fvb1 : p.fmb1;
  const float* hw2 = role ? p.fvw2 : p.fmw2;
  const float* hb2 = role ? p.fvb2 : p.fmb2;

  const float Tt = p.Tin[t];
  const size_t c_off = (role ? OFF_CT1 : OFF_CT) + (size_t)t * 128;

  // ---- encoder
  // Role 0 (binarized Ct): full f64 path -> 128-bit mask + direct Ct store.
  //   The <0.1 decision must match an f64 numpy reference; f32 fma noise
  //   (~1e-8) flips knife-edge elements (round-1 failure, absmax==1.0).
  // Role 1 (continuous Ct_1): f32 e1 kept for the per-node loop.
  float e1[8];
  unsigned cmask[4] = {0u, 0u, 0u, 0u};
  if (role == 0) {
    double e0d[8], e1d[8];
    const double Td = (double)Tt;
    #pragma unroll
    for (int j = 0; j < 8; ++j) {
      double v = Td * (double)ew0[j] + (double)eb0[j];
      e0d[j] = v < 0.0 ? 0.01 * v : v;
    }
    #pragma unroll
    for (int j = 0; j < 8; ++j) {
      double v = (double)eb1[j];
      #pragma unroll
      for (int i = 0; i < 8; ++i) v = fma(e0d[i], (double)ew1[i * 8 + j], v);
      e1d[j] = v < 0.0 ? 0.01 * v : v;
    }
    #pragma unroll 1
    for (int n = 0; n < 16; ++n) {
      float cb[8];
      #pragma unroll
      for (int k = 0; k < 8; ++k) {
        double s = (double)eb2[n * 8 + k];
        #pragma unroll
        for (int i = 0; i < 8; ++i)
          s = fma(e1d[i], (double)ew2[i * 128 + n * 8 + k], s);
        const int bit = (s < 0.1) ? 0 : 1;
        cb[k] = bit ? 1.f : 0.f;
        const int idx = n * 8 + k;
        cmask[idx >> 5] |= (unsigned)bit << (idx & 31);
      }
      store8(p.out + c_off + (size_t)n * 8, cb);
    }
  } else {
    float e0[8];
    #pragma unroll
    for (int j = 0; j < 8; ++j) {
      float v = fmaf(Tt, ew0[j], eb0[j]);
      e0[j] = v < 0.f ? 0.01f * v : v;
    }
    #pragma unroll
    for (int j = 0; j < 8; ++j) {
      float v = eb1[j];
      #pragma unroll
      for (int i = 0; i < 8; ++i) v = fmaf(e0[i], ew1[i * 8 + j], v);
      e1[j] = v < 0.f ? 0.01f * v : v;
    }
  }

  // ---- latent loads
  float dlm0[8], dlm1[8], dlv0[8], dlv1[8];   // decode inputs
  float hx0[8], hx1[8];                        // head inputs
  if (role == 0) {
    load8(p.lm + (size_t)t * 8, dlm0);
    load8(p.lm + (size_t)TL * 8 + (size_t)t * 8, dlm1);
    load8(p.lv + (size_t)t * 8, dlv0);
    load8(p.lv + (size_t)TL * 8 + (size_t)t * 8, dlv1);
    #pragma unroll
    for (int j = 0; j < 8; ++j) { hx0[j] = dlm0[j]; hx1[j] = dlm1[j]; }
  } else {
    if (t > 0) {
      load8(p.lm + (size_t)(t - 1) * 8, dlm0);
      load8(p.lm + (size_t)TL * 8 + (size_t)(t - 1) * 8, dlm1);
      load8(p.lv + (size_t)(t - 1) * 8, dlv0);
      load8(p.lv + (size_t)TL * 8 + (size_t)(t - 1) * 8, dlv1);
    } else {
      #pragma unroll
      for (int j = 0; j < 8; ++j) { dlm0[j]=0.f; dlm1[j]=0.f; dlv0[j]=0.f; dlv1[j]=0.f; }
    }
    load8(p.lv + (size_t)t * 8, hx0);
    load8(p.lv + (size_t)TL * 8 + (size_t)t * 8, hx1);
  }

  // ---- head: x -> relu(x@w1+b1) @ w2 + b2  (fused, no h[128] storage)
  {
    const size_t hoff = (role ? OFF_LVP : OFF_LMP) + (size_t)t * 8;
    #pragma unroll
    for (int l = 0; l < 2; ++l) {
      const float* hx = l ? hx1 : hx0;
      float o8[8];
      #pragma unroll
      for (int j = 0; j < 8; ++j) o8[j] = hb2[j];
      #pragma unroll 4
      for (int o = 0; o < 128; ++o) {
        float a = hb1[o];
        #pragma unroll
        for (int f = 0; f < 8; ++f) a = fmaf(hx[f], hw1[f * 128 + o], a);
        a = fmaxf(a, 0.f);
        #pragma unroll
        for (int j = 0; j < 8; ++j) o8[j] = fmaf(a, hw2[o * 8 + j], o8[j]);
      }
      store8(p.out + hoff + (size_t)l * TL * 8, o8);
    }
  }

  // ---- per-node: C gate + decode MLP (32 -> 64 -> dot w12)
  const size_t r_off = (role ? OFF_PRED : OFF_RECON) + (size_t)t * 16;

  #pragma unroll 1
  for (int n = 0; n < 16; ++n) {
    float c[8];
    if (role == 0) {
      #pragma unroll
      for (int k = 0; k < 8; ++k) {
        const int idx = n * 8 + k;
        c[k] = ((cmask[idx >> 5] >> (idx & 31)) & 1u) ? 1.f : 0.f;
      }
    } else {
      #pragma unroll
      for (int k = 0; k < 8; ++k) {
        float s = eb2[n * 8 + k];
        #pragma unroll
        for (int i = 0; i < 8; ++i) s = fmaf(e1[i], ew2[i * 128 + n * 8 + k], s);
        c[k] = s;
      }
      store8(p.out + c_off + (size_t)n * 8, c);
    }

    // features x[f]: f=2k+l -> c[k]*lm_l[k]; f=16+2k+l -> c[k]*lv_l[k]
    float x[32];
    #pragma unroll
    for (int k = 0; k < 8; ++k) {
      x[2 * k]      = c[k] * dlm0[k];
      x[2 * k + 1]  = c[k] * dlm1[k];
      x[16 + 2 * k] = c[k] * dlv0[k];
      x[17 + 2 * k] = c[k] * dlv1[k];
    }

    // wave-uniform skip mask (recon only; Ct mostly binarizes to 0)
    unsigned kmask = 0xffu;
    if (role == 0) {
      unsigned m = 0;
      #pragma unroll
      for (int k = 0; k < 8; ++k)
        m |= (__ballot(c[k] != 0.f) != 0ull ? 1u : 0u) << k;
      kmask = m;
    }

    float s = s_b12[n];
    const float* wb   = p.lw0 + (size_t)n * 2048;
    const float* lb   = p.lb0 + n * 64;
    const float* w12n = &s_w12[n * 64];

    #pragma unroll 1
    for (int ob = 0; ob < 64; ob += 16) {
      float acc[16];
      #pragma unroll
      for (int j = 0; j < 16; ++j) acc[j] = lb[ob + j];
      #pragma unroll
      for (int k = 0; k < 8; ++k) {
        if (kmask & (1u << k)) {
          const float x0 = x[2 * k], x1 = x[2 * k + 1];
          const float x2 = x[16 + 2 * k], x3 = x[17 + 2 * k];
          const float* r0 = wb + (2 * k) * 64 + ob;   // rows 2k, 2k+1, 16+2k, 17+2k
          #pragma unroll
          for (int j = 0; j < 16; ++j) {
            float a = acc[j];
            a = fmaf(x0, r0[j], a);
            a = fmaf(x1, r0[64 + j], a);
            a = fmaf(x2, r0[1024 + j], a);
            a = fmaf(x3, r0[1088 + j], a);
            acc[j] = a;
          }
        }
      }
      #pragma unroll
      for (int j = 0; j < 16; ++j)
        s = fmaf(fmaxf(acc[j], 0.f), w12n[ob + j], s);
    }
    p.out[r_off + n] = fmaxf(s, 0.f);
  }
}

extern "C" void kernel_launch(void* const* d_in, const int* in_sizes, int n_in,
                              void* d_out, int out_size, void* d_ws, size_t ws_size,
                              hipStream_t stream) {
  Params p;
  p.lm   = (const float*)d_in[0];
  p.lv   = (const float*)d_in[1];
  p.Tin  = (const float*)d_in[2];
  p.cw0  = (const float*)d_in[3];  p.cb0 = (const float*)d_in[4];
  p.cw1  = (const float*)d_in[5];  p.cb1 = (const float*)d_in[6];
  p.cw2  = (const float*)d_in[7];  p.cb2 = (const float*)d_in[8];
  p.pw0  = (const float*)d_in[9];  p.pb0 = (const float*)d_in[10];
  p.pw1  = (const float*)d_in[11]; p.pb1 = (const float*)d_in[12];
  p.pw2  = (const float*)d_in[13]; p.pb2 = (const float*)d_in[14];
  p.fmw1 = (const float*)d_in[15]; p.fmb1 = (const float*)d_in[16];
  p.fmw2 = (const float*)d_in[17]; p.fmb2 = (const float*)d_in[18];
  p.fvw1 = (const float*)d_in[19]; p.fvb1 = (const float*)d_in[20];
  p.fvw2 = (const float*)d_in[21]; p.fvb2 = (const float*)d_in[22];
  p.lw0  = (const float*)d_in[23]; p.lb0 = (const float*)d_in[24];
  p.lw1  = (const float*)d_in[25]; p.lb1 = (const float*)d_in[26];
  p.lw2  = (const float*)d_in[27]; p.lb2 = (const float*)d_in[28];
  p.out  = (float*)d_out;

  tld_fused<<<dim3(TL / 128), dim3(256), 0, stream>>>(p);
}